// Round 8
// baseline (234.501 us; speedup 1.0000x reference)
//
#include <hip/hip_runtime.h>
#include <cstddef>
#include <cstdint>

typedef float f32x4 __attribute__((ext_vector_type(4)));
typedef short bf16x8 __attribute__((ext_vector_type(8)));

__device__ __forceinline__ float fast_exp2(float x) { return __builtin_amdgcn_exp2f(x); }
__device__ __forceinline__ float fast_log2(float x) { return __builtin_amdgcn_logf(x); }

__device__ __forceinline__ short bf16rne(float x) {
  uint32_t u = __float_as_uint(x);
  u += 0x7fffu + ((u >> 16) & 1u);
  return (short)(u >> 16);
}

namespace {
constexpr int Bc = 256, Tc = 1024, Kc = 128;
constexpr int NC = 32;          // time chunks -> 512 one-wave blocks = 2 per CU
constexpr int WARM = 12;        // Birkhoff warmup (R2..R7-proven, absmax 0.0)
constexpr int MEAS = 1023 - WARM;  // 1011; s_c = floor(1011*c/32), L in {31,32}
constexpr float L2E = 1.4426950408889634f;
constexpr float LN2 = 0.6931471805599453f;
constexpr int WS_ET2 = NC * Bc;    // float offset of permuted exp(trans)
// ws: contrib[32][256] floats (32KB) + ET2p bf16[128][128] (32KB) = 64KB.
}

// R7 post-mortem: coalescing was NEUTRAL (82.5 -> 90us). Cross-round model
// that fits R1/R2/R5/R6/R7 within noise: time = total demand / ~3.3 TB/s
// (the fabric's rate for this scattered 512B-granule pattern; streaming=6.3).
// Delivered B/cyc/CU was 5.1-6.8 across five structures -> structural
// micro-opts can't move it. Levers: (a) CUT DEMAND, (b) contiguity + slack.
//
// This round: NC 96 -> 32 (overlap x2.2 -> x1.45, demand 283 -> ~185MB);
// LDS ring depth 3 -> 8 rows (64KB, 2 blocks/CU exactly matches the 512-block
// grid); issue granule = 1KB FULLY CONTIGUOUS (2 consecutive t-rows of one
// batch row per global_load_lds; 16 insts per 2 steps, issued at odd steps
// covering rows T+6,T+7). Counted waits: vmcnt(48) after odd-step issue /
// vmcnt(32) at even steps (3 resp. 2 batches of 16 stay in flight; never 0);
// slack = 6 steps. Static clamp R->43 keeps every touched address <= row
// s0+44 <= 1023 (all chunks); clamped pairs land only in dead slots
// (verified per-slot: live rows <= NSTEPS always come from unclamped pairs).
//
// Compute core (R6/R7-verified, byte-identical): position permutation phi
// folded into A so MFMA C registers ARE the next B operand; per step 32 MFMA
// + 32 fused exp2(e*L2E+sf) + packs + one __shfl for the lag-1 pow2 rescale.
// Telescope: chunk c warm-starts (ones) at s_c, Amid at s_c+12, Aend at
// s_{c+1}+12; chunk 0 exact-start, chunk 31 end-weighted.
// logZ = LN2*[Aend^0 + sum(Aend-Amid)].
__global__ __launch_bounds__(128, 1) void crf_prep(
    const float* __restrict__ trans, float* __restrict__ ws)
{
  unsigned short* et = reinterpret_cast<unsigned short*>(ws + WS_ET2);
  const int m = (int)blockIdx.x;   // output tag row 0..127
  const int c = (int)threadIdx.x;  // permuted k position 0..127
  // tau: bits 0,1,5,6 identity; tau bit4 <- c bit2; tau bits2,3 <- c bits3,4.
  const int tau = (c & 0x63) | ((c & 4) << 2) | ((c & 0x18) >> 1);
  et[(size_t)m * Kc + c] =
      (unsigned short)bf16rne(fast_exp2(trans[(size_t)tau * Kc + m] * L2E));
}

__global__ __launch_bounds__(64) void crf_chunk_kernel(
    const float* __restrict__ hs,
    const float* __restrict__ start_t,
    const float* __restrict__ end_t,
    float* __restrict__ ws)
{
  // Ring: 4 pair-slots x 16 batch rows x 1KB (rows 2k+1,2k+2 share a slot).
  __shared__ __align__(16) float ering[4][16][256];   // 64 KB

  const int lane = (int)threadIdx.x;
  const int b = lane & 15;               // batch row within group (compute role)
  const int q = lane >> 4;               // quad group 0..3 (compute role)
  const int b7 = b & 7;
  const int h2v = (lane >> 5) * 128;     // load role: t-half within 1KB granule
  const int s31 = lane & 31;             // load role: 16B slice within 512B row
  const int rb = (int)blockIdx.x & 15;   // batch group
  const int ck = (int)blockIdx.x >> 4;   // time chunk 0..31
  const int brow = rb * 16 + b;
  const int s0 = (MEAS * ck) / NC;
  const int L  = (MEAS * (ck + 1)) / NC - s0;   // 31 or 32
  const float* __restrict__ eb = hs + (size_t)brow * Tc * Kc + (size_t)s0 * Kc;
  const float* __restrict__ hb = hs + (size_t)(rb * 16) * (Tc * Kc) + (size_t)s0 * Kc;
  const unsigned short* __restrict__ et =
      reinterpret_cast<const unsigned short*>(ws + WS_ET2);

  // A-frags: Ap[nt][tt] = ET2p row (16nt+b), cols 32tt+8q..+7 (one-time setup).
  bf16x8 Ap[8][4];
#pragma unroll
  for (int nt = 0; nt < 8; ++nt)
#pragma unroll
    for (int tt = 0; tt < 4; ++tt)
      Ap[nt][tt] = *(const bf16x8*)&et[(size_t)(16 * nt + b) * Kc + 32 * tt + 8 * q];

  // Bf init in phi-storage (R6-verified). ck==0 exact; else ones.
  bf16x8 Bf[4];
  if (ck == 0) {
#pragma unroll
    for (int tt = 0; tt < 4; ++tt) {
      f32x4 sv0 = *(const f32x4*)&start_t[32 * tt + 4 * q];
      f32x4 sv1 = *(const f32x4*)&start_t[32 * tt + 4 * q + 16];
      f32x4 e0v = *(const f32x4*)&eb[32 * tt + 4 * q];
      f32x4 e1v = *(const f32x4*)&eb[32 * tt + 4 * q + 16];
      bf16x8 v;
      v[0] = bf16rne(fast_exp2((sv0.x + e0v.x) * L2E));
      v[1] = bf16rne(fast_exp2((sv0.y + e0v.y) * L2E));
      v[2] = bf16rne(fast_exp2((sv0.z + e0v.z) * L2E));
      v[3] = bf16rne(fast_exp2((sv0.w + e0v.w) * L2E));
      v[4] = bf16rne(fast_exp2((sv1.x + e1v.x) * L2E));
      v[5] = bf16rne(fast_exp2((sv1.y + e1v.y) * L2E));
      v[6] = bf16rne(fast_exp2((sv1.z + e1v.z) * L2E));
      v[7] = bf16rne(fast_exp2((sv1.w + e1v.w) * L2E));
      Bf[tt] = v;
    }
  } else {
    const short one = (short)0x3F80;
#pragma unroll
    for (int tt = 0; tt < 4; ++tt) {
      bf16x8 v;
#pragma unroll
      for (int j = 0; j < 8; ++j) v[j] = one;
      Bf[tt] = v;
    }
  }

  float sf = 0.f;    // log2 of carried scale (lag-1, exact integer)
  int curE0 = 0;
  int Mi = 0;
  f32x4 er[8];       // current emission row, per-(b,q) slices
  f32x4 P[8];        // post-emission state, TRUE tag (16nt+4q+r), f32

// Issue pair (RR, RR+1), RR odd literal: 16 insts, one batch row each, 1KB
// contiguous. Source slice pre-XOR'd by (i&7) (involution; same XOR on read).
// Static clamp RR->43: max touched row = s0+44 <= 1023 for all chunks; the
// clamp only fires for pairs whose rows are never read (dead-slot-verified).
#define RING_ISSUE(RR) do {                                                     \
    constexpr int Rp_ = ((RR) > 43) ? 43 : (RR);                                \
    constexpr int pr_ = (((RR) + 1) >> 1) & 3;                                  \
    _Pragma("unroll")                                                           \
    for (int i = 0; i < 16; ++i) {                                              \
      const float* src_ = hb + (size_t)i * (Tc * Kc) + (size_t)Rp_ * Kc         \
                        + (size_t)(h2v + ((s31 ^ (i & 7)) << 2));               \
      __builtin_amdgcn_global_load_lds(                                         \
          (const __attribute__((address_space(1))) uint32_t*)(const void*)src_, \
          (__attribute__((address_space(3))) uint32_t*)(void*)&ering[pr_][i][0],\
          16, 0, 0);                                                            \
    }                                                                           \
  } while (0)

// Read row R1 (literal) into er. VC = counted vmcnt (batches newer than R1's
// pair stay in flight). Row R1 lives in pair ((R1+1)>>1)&3, half (R1+1)&1.
#define RING_READ(R1, VC) do {                                                  \
    asm volatile("s_waitcnt vmcnt(" #VC ")" ::: "memory");                      \
    constexpr int prr_ = (((R1) + 1) >> 1) & 3;                                 \
    constexpr int hf_ = ((R1) + 1) & 1;                                         \
    const float* rp_ = &ering[prr_][0][0];                                      \
    _Pragma("unroll")                                                           \
    for (int nt = 0; nt < 8; ++nt)                                              \
      er[nt] = *(const f32x4*)&rp_[b * 256 + hf_ * 128 + (((4 * nt + q) ^ b7) << 2)]; \
  } while (0)

// One step, literal T. Odd steps: lgkmcnt(0) closes the ds_read-vs-overwrite
// WAR (slot last read 2 steps ago), then issue pair (T+6,T+7).
#define STEP(T) do {                                                            \
    if ((T) & 1) {                                                              \
      asm volatile("s_waitcnt lgkmcnt(0)" ::: "memory");                        \
      RING_ISSUE((T) + 6);                                                      \
    }                                                                           \
    const f32x4 z4 = {0.f, 0.f, 0.f, 0.f};                                      \
    Mi += curE0;                                                                \
    float c00src = 0.f;                                                         \
    _Pragma("unroll")                                                           \
    for (int nt = 0; nt < 8; ++nt) {                                            \
      f32x4 c01 = __builtin_amdgcn_mfma_f32_16x16x32_bf16(Ap[nt][1], Bf[1],     \
          __builtin_amdgcn_mfma_f32_16x16x32_bf16(Ap[nt][0], Bf[0], z4, 0, 0, 0), \
          0, 0, 0);                                                             \
      f32x4 c23 = __builtin_amdgcn_mfma_f32_16x16x32_bf16(Ap[nt][3], Bf[3],     \
          __builtin_amdgcn_mfma_f32_16x16x32_bf16(Ap[nt][2], Bf[2], z4, 0, 0, 0), \
          0, 0, 0);                                                             \
      f32x4 cv = c01 + c23;                                                     \
      if (nt == 0) c00src = cv.x;                                               \
      f32x4 e = er[nt];                                                         \
      f32x4 p;                                                                  \
      p.x = cv.x * fast_exp2(__builtin_fmaf(e.x, L2E, sf));                     \
      p.y = cv.y * fast_exp2(__builtin_fmaf(e.y, L2E, sf));                     \
      p.z = cv.z * fast_exp2(__builtin_fmaf(e.z, L2E, sf));                     \
      p.w = cv.w * fast_exp2(__builtin_fmaf(e.w, L2E, sf));                     \
      P[nt] = p;                                                                \
    }                                                                           \
    float c00 = __shfl(c00src, b, 64);  /* tag0 value for batch b */            \
    _Pragma("unroll")                                                           \
    for (int tt = 0; tt < 4; ++tt) {                                            \
      bf16x8 v;                                                                 \
      v[0] = bf16rne(P[2 * tt].x);     v[1] = bf16rne(P[2 * tt].y);             \
      v[2] = bf16rne(P[2 * tt].z);     v[3] = bf16rne(P[2 * tt].w);             \
      v[4] = bf16rne(P[2 * tt + 1].x); v[5] = bf16rne(P[2 * tt + 1].y);         \
      v[6] = bf16rne(P[2 * tt + 1].z); v[7] = bf16rne(P[2 * tt + 1].w);         \
      Bf[tt] = v;                                                               \
    }                                                                           \
    {                                                                           \
      uint32_t ex = (__float_as_uint(c00) >> 23) & 0xffu;                       \
      curE0 = (int)ex - 127;                                                    \
      sf = (float)(127 - (int)ex);                                              \
    }                                                                           \
    if ((T) & 1) { RING_READ((T) + 1, 48); } else { RING_READ((T) + 1, 32); }   \
  } while (0)

// A = Mi + log2(sum_tags P) per batch row; valid on lanes with q==0 (lane<16).
#define MEASURE(DST, WEIGHTED) do {                                             \
    float part = 0.f;                                                           \
    if (WEIGHTED) {                                                             \
      _Pragma("unroll")                                                         \
      for (int nt = 0; nt < 8; ++nt) {                                          \
        f32x4 ev = *(const f32x4*)&end_t[16 * nt + 4 * q];                      \
        part += P[nt].x * fast_exp2(ev.x * L2E) + P[nt].y * fast_exp2(ev.y * L2E) \
              + P[nt].z * fast_exp2(ev.z * L2E) + P[nt].w * fast_exp2(ev.w * L2E); \
      }                                                                         \
    } else {                                                                    \
      _Pragma("unroll")                                                         \
      for (int nt = 0; nt < 8; ++nt)                                            \
        part += P[nt].x + P[nt].y + P[nt].z + P[nt].w;                          \
    }                                                                           \
    part += __shfl_xor(part, 16);                                               \
    part += __shfl_xor(part, 32);                                               \
    DST = (float)Mi + fast_log2(part);                                          \
  } while (0)

  // Prologue: issue pairs (1,2),(3,4),(5,6); counted-wait; slice row 1.
  RING_ISSUE(1);
  RING_ISSUE(3);
  RING_ISSUE(5);
  RING_READ(1, 32);

  // Phase 1: local steps 1..12 (warmup; measured for ck==0), then Amid.
  STEP(1);  STEP(2);  STEP(3);  STEP(4);
  STEP(5);  STEP(6);  STEP(7);  STEP(8);
  STEP(9);  STEP(10); STEP(11); STEP(12);
  float Amid; MEASURE(Amid, false);

  // Phase 2: local steps 13..12+L (L in {31,32}).
  STEP(13); STEP(14); STEP(15); STEP(16);
  STEP(17); STEP(18); STEP(19); STEP(20);
  STEP(21); STEP(22); STEP(23); STEP(24);
  STEP(25); STEP(26); STEP(27); STEP(28);
  STEP(29); STEP(30); STEP(31); STEP(32);
  STEP(33); STEP(34); STEP(35); STEP(36);
  STEP(37); STEP(38); STEP(39); STEP(40);
  STEP(41); STEP(42); STEP(43);
  if (L == 32) { STEP(44); }
  float Aend; MEASURE(Aend, (ck == NC - 1));

#undef STEP
#undef MEASURE
#undef RING_ISSUE
#undef RING_READ

  if (lane < 16)
    ws[(size_t)ck * Bc + brow] = Aend - (ck ? Amid : 0.f);
}

// logZ_b = ln2 * sum_c contrib[c][b]
__global__ __launch_bounds__(256, 1) void crf_combine(
    const float* __restrict__ ws, float* __restrict__ out)
{
  const int b = (int)threadIdx.x;
  float s = 0.f;
#pragma unroll
  for (int cc = 0; cc < NC; ++cc) s += ws[(size_t)cc * Bc + b];
  out[b] = s * LN2;
}

extern "C" void kernel_launch(void* const* d_in, const int* in_sizes, int n_in,
                              void* d_out, int out_size, void* d_ws, size_t ws_size,
                              hipStream_t stream) {
  const float* hs    = (const float*)d_in[0];
  const float* trans = (const float*)d_in[1];
  const float* st    = (const float*)d_in[2];
  const float* en    = (const float*)d_in[3];
  float* ws = (float*)d_ws;   // needs 8192 + 8192 floats = 64 KB
  crf_prep<<<dim3(Kc), dim3(Kc), 0, stream>>>(trans, ws);
  crf_chunk_kernel<<<dim3(NC * 16), dim3(64), 0, stream>>>(hs, st, en, ws);
  crf_combine<<<dim3(1), dim3(Bc), 0, stream>>>(ws, (float*)d_out);
}